// Round 7
// baseline (178.337 us; speedup 1.0000x reference)
//
#include <hip/hip_runtime.h>

// GCN layer: out = relu( G(feature) @ W^T + b ), G = mean over in-edges (or
// identity for isolated nodes).  N=50000, F=64, E=800000.
//
// Structure: GEMM commutes with the (linear) aggregation:
//   G(feature) @ W^T == G(feature @ W^T)
// so we precompute Y = feature @ W^T as a dense coalesced GEMM (k_gemm), and
// the gather kernel is pure gather-mean + bias + relu (no LDS, no barriers).
// Sort is rank-based: rank[e]=atomicAdd(deg[dst]) pass, single-block scan,
// atomic-free bucket scatter.
// Round-7 fix: k_gemm feature staging was 32x8 float4 (half of each 16-float4
// row) -> columns 32..63 of LDS uninitialized -> absmax 5e4. Now 512 float4
// staged via strided loop.

#define F 64

// ---------- K1: degree histogram + per-edge rank ----------
__global__ __launch_bounds__(256) void k_deg(const int* __restrict__ edst,
                                             int* __restrict__ deg,
                                             int* __restrict__ rank, int E) {
    int base = (blockIdx.x * 256 + threadIdx.x) * 4;
    if (base + 3 < E) {
        int4 d4 = *(const int4*)(edst + base);
        int r0 = atomicAdd(&deg[d4.x], 1);
        int r1 = atomicAdd(&deg[d4.y], 1);
        int r2 = atomicAdd(&deg[d4.z], 1);
        int r3 = atomicAdd(&deg[d4.w], 1);
        *(int4*)(rank + base) = make_int4(r0, r1, r2, r3);
    } else {
        for (int e = base; e < E; ++e)
            rank[e] = atomicAdd(&deg[edst[e]], 1);
    }
}

// ---------- K2: single-block exclusive scan over N degrees ----------
__global__ __launch_bounds__(1024) void k_scan(const int* __restrict__ deg,
                                               int* __restrict__ off, int N, int E) {
    int tid = threadIdx.x;
    int chunk = (N + 1023) >> 10;
    int i0 = tid * chunk;
    int i1 = min(i0 + chunk, N);
    int s = 0;
    for (int i = i0; i < i1; ++i) s += deg[i];
    __shared__ int sc[1024];
    sc[tid] = s;
    __syncthreads();
    for (int d = 1; d < 1024; d <<= 1) {
        int t = (tid >= d) ? sc[tid - d] : 0;
        __syncthreads();
        sc[tid] += t;
        __syncthreads();
    }
    int run = sc[tid] - s;   // exclusive prefix of this thread's chunk
    for (int i = i0; i < i1; ++i) { off[i] = run; run += deg[i]; }
    if (tid == 0) off[N] = E;
}

// ---------- K3: atomic-free bucket scatter ----------
__global__ __launch_bounds__(256) void k_bucket(const int* __restrict__ esrc,
                                                const int* __restrict__ edst,
                                                const int* __restrict__ off,
                                                const int* __restrict__ rank,
                                                int* __restrict__ bucket, int E) {
    int base = (blockIdx.x * 256 + threadIdx.x) * 4;
    if (base + 3 < E) {
        int4 d4 = *(const int4*)(edst + base);
        int4 r4 = *(const int4*)(rank + base);
        int4 s4 = *(const int4*)(esrc + base);
        bucket[off[d4.x] + r4.x] = s4.x;
        bucket[off[d4.y] + r4.y] = s4.y;
        bucket[off[d4.z] + r4.z] = s4.z;
        bucket[off[d4.w] + r4.w] = s4.w;
    } else {
        for (int e = base; e < E; ++e)
            bucket[off[edst[e]] + rank[e]] = esrc[e];
    }
}

// ---------- K4: Y = feature @ W^T (dense, coalesced) ----------
// 32 nodes/block; thread = (npair 0..15, foq 0..15) -> 2 nodes x 4 out-feats.
// sWt[k*76+fo] = W[fo][k]. shh rows padded to 72.
__global__ __launch_bounds__(256) void k_gemm(const float* __restrict__ feature,
                                              const float* __restrict__ W,
                                              float* __restrict__ Y, int N) {
    __shared__ float sWt[64 * 76];
    __shared__ float shh[32 * 72];
    int tid = threadIdx.x;
    for (int i = tid; i < 4096; i += 256) {
        int fo = i >> 6, k = i & 63;
        sWt[k * 76 + fo] = W[i];
    }
    int n0blk = blockIdx.x * 32;
    // stage 32 rows x 16 float4 (full 64-float rows), 2 float4 per thread
    for (int i = tid; i < 512; i += 256) {
        int r = i >> 4, c4 = i & 15;
        int n = n0blk + r;
        float4 v = make_float4(0.f, 0.f, 0.f, 0.f);
        if (n < N) v = ((const float4*)feature)[(long)n * 16 + c4];
        *(float4*)&shh[r * 72 + c4 * 4] = v;
    }
    __syncthreads();
    int npair = tid >> 4, foq = tid & 15;
    int r0 = npair * 2, r1 = r0 + 1;
    float a0=0,a1=0,a2=0,a3=0,b0=0,b1=0,b2=0,b3=0;
#pragma unroll 8
    for (int k = 0; k < 64; ++k) {
        float hA = shh[r0 * 72 + k];
        float hB = shh[r1 * 72 + k];
        float4 wv = *(const float4*)&sWt[k * 76 + foq * 4];
        a0 = fmaf(hA, wv.x, a0); a1 = fmaf(hA, wv.y, a1);
        a2 = fmaf(hA, wv.z, a2); a3 = fmaf(hA, wv.w, a3);
        b0 = fmaf(hB, wv.x, b0); b1 = fmaf(hB, wv.y, b1);
        b2 = fmaf(hB, wv.z, b2); b3 = fmaf(hB, wv.w, b3);
    }
    int nA = n0blk + r0, nB = n0blk + r1;
    if (nA < N) ((float4*)Y)[(long)nA * 16 + foq] = make_float4(a0, a1, a2, a3);
    if (nB < N) ((float4*)Y)[(long)nB * 16 + foq] = make_float4(b0, b1, b2, b3);
}

// ---------- K5: gather-mean over Y + bias + relu (no LDS, no barriers) ----
__global__ __launch_bounds__(256) void k_gather(const float* __restrict__ Y,
                                                const int* __restrict__ off,
                                                const int* __restrict__ bucket,
                                                const float* __restrict__ bias,
                                                float* __restrict__ out, int N) {
    int tid = threadIdx.x;
    int w = tid >> 6, lane = tid & 63;
    int g = lane >> 4, c = lane & 15;
    int n = blockIdx.x * 4 + w;
    if (n >= N) return;
    int beg = off[n], end = off[n + 1];
    int d = end - beg;
    const float4* Y4 = (const float4*)Y;
    float4 A = make_float4(0.f,0.f,0.f,0.f), B = A, C = A, Dv = A;
    int last = end - 1;
    for (int base = beg; base < end; base += 16) {
        int j0 = base + g, j1 = j0 + 4, j2 = j0 + 8, j3 = j0 + 12;
        int s0 = bucket[min(j0, last)];      // clamped: loads unconditional,
        int s1 = bucket[min(j1, last)];      // 4 chains in flight
        int s2 = bucket[min(j2, last)];
        int s3 = bucket[min(j3, last)];
        float4 v0 = Y4[(long)s0 * 16 + c];
        float4 v1 = Y4[(long)s1 * 16 + c];
        float4 v2 = Y4[(long)s2 * 16 + c];
        float4 v3 = Y4[(long)s3 * 16 + c];
        if (j0 < end) { A.x += v0.x; A.y += v0.y; A.z += v0.z; A.w += v0.w; }
        if (j1 < end) { B.x += v1.x; B.y += v1.y; B.z += v1.z; B.w += v1.w; }
        if (j2 < end) { C.x += v2.x; C.y += v2.y; C.z += v2.z; C.w += v2.w; }
        if (j3 < end) { Dv.x += v3.x; Dv.y += v3.y; Dv.z += v3.z; Dv.w += v3.w; }
    }
    A.x += B.x + C.x + Dv.x;
    A.y += B.y + C.y + Dv.y;
    A.z += B.z + C.z + Dv.z;
    A.w += B.w + C.w + Dv.w;
    A.x += __shfl_xor(A.x, 16); A.x += __shfl_xor(A.x, 32);
    A.y += __shfl_xor(A.y, 16); A.y += __shfl_xor(A.y, 32);
    A.z += __shfl_xor(A.z, 16); A.z += __shfl_xor(A.z, 32);
    A.w += __shfl_xor(A.w, 16); A.w += __shfl_xor(A.w, 32);
    int fw = c * 4 + g;
    float hv;
    if (d > 0) {
        float sel = (g == 0) ? A.x : (g == 1) ? A.y : (g == 2) ? A.z : A.w;
        hv = sel / (float)d;
    } else {
        hv = Y[(long)n * F + fw];            // isolated node: Y row directly
    }
    out[(long)n * F + fw] = fmaxf(hv + bias[fw], 0.0f);
}

// ---------- fallback tier B: fused gather+GEMM (round-5 k_node) ----------
__global__ __launch_bounds__(256) void k_node_fused(const float* __restrict__ feature,
                                                    const int* __restrict__ off,
                                                    const int* __restrict__ bucket,
                                                    const float* __restrict__ W,
                                                    const float* __restrict__ bias,
                                                    float* __restrict__ out, int N) {
    __shared__ float sWt[64 * 65];
    __shared__ float sh[4][64];
    int tid = threadIdx.x;
    for (int i = tid; i < 64 * 64; i += 256) {
        int fo = i >> 6, k = i & 63;
        sWt[k * 65 + fo] = W[i];
    }
    int w = tid >> 6, lane = tid & 63;
    int g = lane >> 4, c = lane & 15;
    int n = blockIdx.x * 4 + w;
    const float4* F4 = (const float4*)feature;
    if (n < N) {
        int beg = off[n], end = off[n + 1];
        int d = end - beg;
        float ax=0,ay=0,az=0,aw=0,bx=0,by=0,bz=0,bw=0;
        for (int base = beg; base < end; base += 8) {
            int i0 = base + g, i1 = base + 4 + g;
            int s0 = (i0 < end) ? bucket[i0] : 0;
            int s1 = (i1 < end) ? bucket[i1] : 0;
            float4 v0 = F4[(long)s0 * 16 + c];
            float4 v1 = F4[(long)s1 * 16 + c];
            if (i0 < end) { ax += v0.x; ay += v0.y; az += v0.z; aw += v0.w; }
            if (i1 < end) { bx += v1.x; by += v1.y; bz += v1.z; bw += v1.w; }
        }
        ax += bx; ay += by; az += bz; aw += bw;
        ax += __shfl_xor(ax, 16); ax += __shfl_xor(ax, 32);
        ay += __shfl_xor(ay, 16); ay += __shfl_xor(ay, 32);
        az += __shfl_xor(az, 16); az += __shfl_xor(az, 32);
        aw += __shfl_xor(aw, 16); aw += __shfl_xor(aw, 32);
        int fw = c * 4 + g;
        float hv;
        if (d > 0) {
            float sel = (g == 0) ? ax : (g == 1) ? ay : (g == 2) ? az : aw;
            hv = sel / (float)d;
        } else {
            hv = feature[(long)n * F + fw];
        }
        sh[w][fw] = hv;
    }
    __syncthreads();
    float acc = bias[lane];
#pragma unroll
    for (int k = 0; k < 64; ++k)
        acc = fmaf(sh[w][k], sWt[k * 65 + lane], acc);
    if (n < N) out[(long)n * F + lane] = fmaxf(acc, 0.0f);
}

// ---------- fallback tier C: pure atomic ----------
__global__ __launch_bounds__(256) void gcn_edge_scatter(const float* __restrict__ feature,
                                                        const int* __restrict__ esrc,
                                                        const int* __restrict__ edst,
                                                        float* __restrict__ agg,
                                                        float* __restrict__ cnt, int E) {
    int t = blockIdx.x * blockDim.x + threadIdx.x;
    int e = t >> 6, f = t & 63;
    if (e >= E) return;
    atomicAdd(&agg[(long)edst[e] * F + f], feature[(long)esrc[e] * F + f]);
    if (f == 0) atomicAdd(&cnt[edst[e]], 1.0f);
}
__global__ __launch_bounds__(256) void gcn_node_apply(const float* __restrict__ feature,
                                                      const float* __restrict__ W,
                                                      const float* __restrict__ bias,
                                                      const float* __restrict__ cnt,
                                                      float* __restrict__ inout, int N) {
    __shared__ float sWt[64 * 65];
    __shared__ float sh[4][64];
    int tid = threadIdx.x;
    for (int i = tid; i < 64 * 64; i += 256) {
        int fo = i >> 6, k = i & 63;
        sWt[k * 65 + fo] = W[i];
    }
    int w = tid >> 6, f = tid & 63;
    int n = blockIdx.x * 4 + w;
    float h = 0.0f;
    if (n < N) {
        float c = cnt[n];
        h = (c > 0.0f) ? inout[(long)n * F + f] / c : feature[(long)n * F + f];
    }
    sh[w][f] = h;
    __syncthreads();
    float acc = bias[f];
#pragma unroll
    for (int k = 0; k < 64; ++k) acc = fmaf(sh[w][k], sWt[k * 65 + f], acc);
    if (n < N) inout[(long)n * F + f] = fmaxf(acc, 0.0f);
}

extern "C" void kernel_launch(void* const* d_in, const int* in_sizes, int n_in,
                              void* d_out, int out_size, void* d_ws, size_t ws_size,
                              hipStream_t stream) {
    const float* feature = (const float*)d_in[0];
    const int*   esrc    = (const int*)d_in[1];
    const int*   edst    = (const int*)d_in[2];
    const float* W       = (const float*)d_in[3];
    const float* bias    = (const float*)d_in[4];

    int N = in_sizes[0] / F;   // 50000
    int E = in_sizes[1];       // 800000

    auto align256 = [](size_t x) { return (x + 255) & ~(size_t)255; };
    size_t sz_off    = align256((size_t)(N + 1) * sizeof(int));
    size_t sz_deg    = align256((size_t)N * sizeof(int));
    size_t sz_rank   = align256((size_t)E * sizeof(int));
    size_t sz_bucket = align256((size_t)E * sizeof(int));
    size_t sz_Y      = align256((size_t)N * F * sizeof(float));
    size_t need_B = sz_off + sz_deg + sz_rank + sz_bucket;
    size_t need_A = need_B + sz_Y;

    int gE4 = (int)(((size_t)E + 1023) / 1024);   // 4 edges/thread, 256 thr

    if (ws_size >= need_A) {
        char* ws = (char*)d_ws;
        int*   off    = (int*)ws;   ws += sz_off;
        int*   deg    = (int*)ws;   ws += sz_deg;
        int*   rank   = (int*)ws;   ws += sz_rank;
        int*   bucket = (int*)ws;   ws += sz_bucket;
        float* Y      = (float*)ws;

        hipMemsetAsync(deg, 0, (size_t)N * sizeof(int), stream);
        k_deg<<<gE4, 256, 0, stream>>>(edst, deg, rank, E);
        k_scan<<<1, 1024, 0, stream>>>(deg, off, N, E);
        k_bucket<<<gE4, 256, 0, stream>>>(esrc, edst, off, rank, bucket, E);
        k_gemm<<<(N + 31) / 32, 256, 0, stream>>>(feature, W, Y, N);
        k_gather<<<(N + 3) / 4, 256, 0, stream>>>(Y, off, bucket, bias,
                                                  (float*)d_out, N);
    } else if (ws_size >= need_B) {
        char* ws = (char*)d_ws;
        int* off    = (int*)ws;   ws += sz_off;
        int* deg    = (int*)ws;   ws += sz_deg;
        int* rank   = (int*)ws;   ws += sz_rank;
        int* bucket = (int*)ws;

        hipMemsetAsync(deg, 0, (size_t)N * sizeof(int), stream);
        k_deg<<<gE4, 256, 0, stream>>>(edst, deg, rank, E);
        k_scan<<<1, 1024, 0, stream>>>(deg, off, N, E);
        k_bucket<<<gE4, 256, 0, stream>>>(esrc, edst, off, rank, bucket, E);
        k_node_fused<<<(N + 3) / 4, 256, 0, stream>>>(feature, off, bucket, W, bias,
                                                      (float*)d_out, N);
    } else {
        float* agg = (float*)d_out;
        float* cnt = (float*)d_ws;
        hipMemsetAsync(agg, 0, (size_t)N * F * sizeof(float), stream);
        hipMemsetAsync(cnt, 0, (size_t)N * sizeof(float), stream);
        long total = (long)E * F;
        gcn_edge_scatter<<<(int)((total + 255) / 256), 256, 0, stream>>>(
            feature, esrc, edst, agg, cnt, E);
        gcn_node_apply<<<(N + 3) / 4, 256, 0, stream>>>(feature, W, bias, cnt, agg, N);
    }
}

// Round 9
// 109.622 us; speedup vs baseline: 1.6268x; 1.6268x over previous
//
#include <hip/hip_runtime.h>

// GCN layer: out = relu( G(feature) @ W^T + b ), G = mean over in-edges (or
// identity for isolated nodes).  N=50000, F=64, E=800000.
//
// Structure: GEMM commutes with the (linear) aggregation:
//   G(feature) @ W^T == G(feature @ W^T)
// so we precompute Y = feature @ W^T densely (k_gemm); the gather kernel is
// pure gather-mean + bias + relu. Sort is rank-based: rank[e]=atomicAdd(deg)
// then atomic-free bucket scatter.
// Round-8 fix: round-7's single-block k_scan was 76us at 0.15% occupancy
// (1 block serial-chunk scan). Back to the parallel 2-dispatch scan:
// k_part (49 blocks) + k_final (root-scan of <=64 partials fused into wave 0).

#define F 64
#define SCAN_BLK 256
#define SCAN_ELEMS 1024   // elements scanned per block (4 per thread)

// ---------- K1: degree histogram + per-edge rank ----------
__global__ __launch_bounds__(256) void k_deg(const int* __restrict__ edst,
                                             int* __restrict__ deg,
                                             int* __restrict__ rank, int E) {
    int base = (blockIdx.x * 256 + threadIdx.x) * 4;
    if (base + 3 < E) {
        int4 d4 = *(const int4*)(edst + base);
        int r0 = atomicAdd(&deg[d4.x], 1);
        int r1 = atomicAdd(&deg[d4.y], 1);
        int r2 = atomicAdd(&deg[d4.z], 1);
        int r3 = atomicAdd(&deg[d4.w], 1);
        *(int4*)(rank + base) = make_int4(r0, r1, r2, r3);
    } else {
        for (int e = base; e < E; ++e)
            rank[e] = atomicAdd(&deg[edst[e]], 1);
    }
}

// ---------- K2a: per-block partial sums ----------
__global__ __launch_bounds__(SCAN_BLK) void k_part(const int* __restrict__ deg,
                                                   int* __restrict__ part, int N) {
    int b = blockIdx.x, tid = threadIdx.x;
    int i0 = b * SCAN_ELEMS + tid * 4;
    int s = 0;
#pragma unroll
    for (int k = 0; k < 4; ++k) { int i = i0 + k; if (i < N) s += deg[i]; }
    for (int d = 32; d; d >>= 1) s += __shfl_down(s, d);
    __shared__ int red[4];
    int w = tid >> 6;
    if ((tid & 63) == 0) red[w] = s;
    __syncthreads();
    if (tid == 0) part[b] = red[0] + red[1] + red[2] + red[3];
}

// ---------- K2b: block-local scan with fused root scan (nb <= 64) ----------
__global__ __launch_bounds__(SCAN_BLK) void k_final(const int* __restrict__ deg,
                                                    const int* __restrict__ part,
                                                    int* __restrict__ off,
                                                    int N, int E, int nb) {
    int b = blockIdx.x, tid = threadIdx.x;
    // wave 0: exclusive prefix of block partials, pick this block's base
    __shared__ int s_base;
    if (tid < 64) {
        int v = (tid < nb) ? part[tid] : 0;
        for (int d = 1; d < 64; d <<= 1) {
            int t = __shfl_up(v, d);
            if (tid >= d) v += t;
        }
        if (tid == b) s_base = v - ((b < nb) ? part[b] : 0);  // exclusive
    }
    int i0 = b * SCAN_ELEMS + tid * 4;
    int v[4]; int s = 0;
#pragma unroll
    for (int k = 0; k < 4; ++k) { int i = i0 + k; v[k] = (i < N) ? deg[i] : 0; s += v[k]; }
    __shared__ int sc[SCAN_BLK];
    sc[tid] = s;
    __syncthreads();
    for (int d = 1; d < SCAN_BLK; d <<= 1) {
        int t = (tid >= d) ? sc[tid - d] : 0;
        __syncthreads();
        sc[tid] += t;
        __syncthreads();
    }
    int exc = sc[tid] - s;
    int run = s_base + exc;
#pragma unroll
    for (int k = 0; k < 4; ++k) {
        int i = i0 + k;
        if (i < N) { off[i] = run; run += v[k]; }
    }
    if (b == 0 && tid == 0) off[N] = E;
}

// ---------- K3: atomic-free bucket scatter ----------
__global__ __launch_bounds__(256) void k_bucket(const int* __restrict__ esrc,
                                                const int* __restrict__ edst,
                                                const int* __restrict__ off,
                                                const int* __restrict__ rank,
                                                int* __restrict__ bucket, int E) {
    int base = (blockIdx.x * 256 + threadIdx.x) * 4;
    if (base + 3 < E) {
        int4 d4 = *(const int4*)(edst + base);
        int4 r4 = *(const int4*)(rank + base);
        int4 s4 = *(const int4*)(esrc + base);
        bucket[off[d4.x] + r4.x] = s4.x;
        bucket[off[d4.y] + r4.y] = s4.y;
        bucket[off[d4.z] + r4.z] = s4.z;
        bucket[off[d4.w] + r4.w] = s4.w;
    } else {
        for (int e = base; e < E; ++e)
            bucket[off[edst[e]] + rank[e]] = esrc[e];
    }
}

// ---------- K4: Y = feature @ W^T (dense, coalesced) ----------
__global__ __launch_bounds__(256) void k_gemm(const float* __restrict__ feature,
                                              const float* __restrict__ W,
                                              float* __restrict__ Y, int N) {
    __shared__ float sWt[64 * 76];
    __shared__ float shh[32 * 72];
    int tid = threadIdx.x;
    for (int i = tid; i < 4096; i += 256) {
        int fo = i >> 6, k = i & 63;
        sWt[k * 76 + fo] = W[i];
    }
    int n0blk = blockIdx.x * 32;
    for (int i = tid; i < 512; i += 256) {        // 32 rows x 16 float4
        int r = i >> 4, c4 = i & 15;
        int n = n0blk + r;
        float4 v = make_float4(0.f, 0.f, 0.f, 0.f);
        if (n < N) v = ((const float4*)feature)[(long)n * 16 + c4];
        *(float4*)&shh[r * 72 + c4 * 4] = v;
    }
    __syncthreads();
    int npair = tid >> 4, foq = tid & 15;
    int r0 = npair * 2, r1 = r0 + 1;
    float a0=0,a1=0,a2=0,a3=0,b0=0,b1=0,b2=0,b3=0;
#pragma unroll 8
    for (int k = 0; k < 64; ++k) {
        float hA = shh[r0 * 72 + k];
        float hB = shh[r1 * 72 + k];
        float4 wv = *(const float4*)&sWt[k * 76 + foq * 4];
        a0 = fmaf(hA, wv.x, a0); a1 = fmaf(hA, wv.y, a1);
        a2 = fmaf(hA, wv.z, a2); a3 = fmaf(hA, wv.w, a3);
        b0 = fmaf(hB, wv.x, b0); b1 = fmaf(hB, wv.y, b1);
        b2 = fmaf(hB, wv.z, b2); b3 = fmaf(hB, wv.w, b3);
    }
    int nA = n0blk + r0, nB = n0blk + r1;
    if (nA < N) ((float4*)Y)[(long)nA * 16 + foq] = make_float4(a0, a1, a2, a3);
    if (nB < N) ((float4*)Y)[(long)nB * 16 + foq] = make_float4(b0, b1, b2, b3);
}

// ---------- K5: gather-mean over Y + bias + relu ----------
__global__ __launch_bounds__(256) void k_gather(const float* __restrict__ Y,
                                                const int* __restrict__ off,
                                                const int* __restrict__ bucket,
                                                const float* __restrict__ bias,
                                                float* __restrict__ out, int N) {
    int tid = threadIdx.x;
    int w = tid >> 6, lane = tid & 63;
    int g = lane >> 4, c = lane & 15;
    int n = blockIdx.x * 4 + w;
    if (n >= N) return;
    int beg = off[n], end = off[n + 1];
    int d = end - beg;
    const float4* Y4 = (const float4*)Y;
    float4 A = make_float4(0.f,0.f,0.f,0.f), B = A, C = A, Dv = A;
    int last = end - 1;
    for (int base = beg; base < end; base += 16) {
        int j0 = base + g, j1 = j0 + 4, j2 = j0 + 8, j3 = j0 + 12;
        int s0 = bucket[min(j0, last)];
        int s1 = bucket[min(j1, last)];
        int s2 = bucket[min(j2, last)];
        int s3 = bucket[min(j3, last)];
        float4 v0 = Y4[(long)s0 * 16 + c];
        float4 v1 = Y4[(long)s1 * 16 + c];
        float4 v2 = Y4[(long)s2 * 16 + c];
        float4 v3 = Y4[(long)s3 * 16 + c];
        if (j0 < end) { A.x += v0.x; A.y += v0.y; A.z += v0.z; A.w += v0.w; }
        if (j1 < end) { B.x += v1.x; B.y += v1.y; B.z += v1.z; B.w += v1.w; }
        if (j2 < end) { C.x += v2.x; C.y += v2.y; C.z += v2.z; C.w += v2.w; }
        if (j3 < end) { Dv.x += v3.x; Dv.y += v3.y; Dv.z += v3.z; Dv.w += v3.w; }
    }
    A.x += B.x + C.x + Dv.x;
    A.y += B.y + C.y + Dv.y;
    A.z += B.z + C.z + Dv.z;
    A.w += B.w + C.w + Dv.w;
    A.x += __shfl_xor(A.x, 16); A.x += __shfl_xor(A.x, 32);
    A.y += __shfl_xor(A.y, 16); A.y += __shfl_xor(A.y, 32);
    A.z += __shfl_xor(A.z, 16); A.z += __shfl_xor(A.z, 32);
    A.w += __shfl_xor(A.w, 16); A.w += __shfl_xor(A.w, 32);
    int fw = c * 4 + g;
    float hv;
    if (d > 0) {
        float sel = (g == 0) ? A.x : (g == 1) ? A.y : (g == 2) ? A.z : A.w;
        hv = sel / (float)d;
    } else {
        hv = Y[(long)n * F + fw];
    }
    out[(long)n * F + fw] = fmaxf(hv + bias[fw], 0.0f);
}

// ---------- fallback tier B: fused gather+GEMM ----------
__global__ __launch_bounds__(256) void k_node_fused(const float* __restrict__ feature,
                                                    const int* __restrict__ off,
                                                    const int* __restrict__ bucket,
                                                    const float* __restrict__ W,
                                                    const float* __restrict__ bias,
                                                    float* __restrict__ out, int N) {
    __shared__ float sWt[64 * 65];
    __shared__ float sh[4][64];
    int tid = threadIdx.x;
    for (int i = tid; i < 64 * 64; i += 256) {
        int fo = i >> 6, k = i & 63;
        sWt[k * 65 + fo] = W[i];
    }
    int w = tid >> 6, lane = tid & 63;
    int g = lane >> 4, c = lane & 15;
    int n = blockIdx.x * 4 + w;
    const float4* F4 = (const float4*)feature;
    if (n < N) {
        int beg = off[n], end = off[n + 1];
        int d = end - beg;
        float ax=0,ay=0,az=0,aw=0,bx=0,by=0,bz=0,bw=0;
        for (int base = beg; base < end; base += 8) {
            int i0 = base + g, i1 = base + 4 + g;
            int s0 = (i0 < end) ? bucket[i0] : 0;
            int s1 = (i1 < end) ? bucket[i1] : 0;
            float4 v0 = F4[(long)s0 * 16 + c];
            float4 v1 = F4[(long)s1 * 16 + c];
            if (i0 < end) { ax += v0.x; ay += v0.y; az += v0.z; aw += v0.w; }
            if (i1 < end) { bx += v1.x; by += v1.y; bz += v1.z; bw += v1.w; }
        }
        ax += bx; ay += by; az += bz; aw += bw;
        ax += __shfl_xor(ax, 16); ax += __shfl_xor(ax, 32);
        ay += __shfl_xor(ay, 16); ay += __shfl_xor(ay, 32);
        az += __shfl_xor(az, 16); az += __shfl_xor(az, 32);
        aw += __shfl_xor(aw, 16); aw += __shfl_xor(aw, 32);
        int fw = c * 4 + g;
        float hv;
        if (d > 0) {
            float sel = (g == 0) ? ax : (g == 1) ? ay : (g == 2) ? az : aw;
            hv = sel / (float)d;
        } else {
            hv = feature[(long)n * F + fw];
        }
        sh[w][fw] = hv;
    }
    __syncthreads();
    float acc = bias[lane];
#pragma unroll
    for (int k = 0; k < 64; ++k)
        acc = fmaf(sh[w][k], sWt[k * 65 + lane], acc);
    if (n < N) out[(long)n * F + lane] = fmaxf(acc, 0.0f);
}

// ---------- fallback tier C: pure atomic ----------
__global__ __launch_bounds__(256) void gcn_edge_scatter(const float* __restrict__ feature,
                                                        const int* __restrict__ esrc,
                                                        const int* __restrict__ edst,
                                                        float* __restrict__ agg,
                                                        float* __restrict__ cnt, int E) {
    int t = blockIdx.x * blockDim.x + threadIdx.x;
    int e = t >> 6, f = t & 63;
    if (e >= E) return;
    atomicAdd(&agg[(long)edst[e] * F + f], feature[(long)esrc[e] * F + f]);
    if (f == 0) atomicAdd(&cnt[edst[e]], 1.0f);
}
__global__ __launch_bounds__(256) void gcn_node_apply(const float* __restrict__ feature,
                                                      const float* __restrict__ W,
                                                      const float* __restrict__ bias,
                                                      const float* __restrict__ cnt,
                                                      float* __restrict__ inout, int N) {
    __shared__ float sWt[64 * 65];
    __shared__ float sh[4][64];
    int tid = threadIdx.x;
    for (int i = tid; i < 64 * 64; i += 256) {
        int fo = i >> 6, k = i & 63;
        sWt[k * 65 + fo] = W[i];
    }
    int w = tid >> 6, f = tid & 63;
    int n = blockIdx.x * 4 + w;
    float h = 0.0f;
    if (n < N) {
        float c = cnt[n];
        h = (c > 0.0f) ? inout[(long)n * F + f] / c : feature[(long)n * F + f];
    }
    sh[w][f] = h;
    __syncthreads();
    float acc = bias[f];
#pragma unroll
    for (int k = 0; k < 64; ++k) acc = fmaf(sh[w][k], sWt[k * 65 + f], acc);
    if (n < N) inout[(long)n * F + f] = fmaxf(acc, 0.0f);
}

extern "C" void kernel_launch(void* const* d_in, const int* in_sizes, int n_in,
                              void* d_out, int out_size, void* d_ws, size_t ws_size,
                              hipStream_t stream) {
    const float* feature = (const float*)d_in[0];
    const int*   esrc    = (const int*)d_in[1];
    const int*   edst    = (const int*)d_in[2];
    const float* W       = (const float*)d_in[3];
    const float* bias    = (const float*)d_in[4];

    int N = in_sizes[0] / F;   // 50000
    int E = in_sizes[1];       // 800000

    auto align256 = [](size_t x) { return (x + 255) & ~(size_t)255; };
    size_t sz_off    = align256((size_t)(N + 1) * sizeof(int));
    size_t sz_deg    = align256((size_t)N * sizeof(int));
    size_t sz_rank   = align256((size_t)E * sizeof(int));
    size_t sz_bucket = align256((size_t)E * sizeof(int));
    size_t sz_part   = align256(64 * sizeof(int));
    size_t sz_Y      = align256((size_t)N * F * sizeof(float));
    size_t need_B = sz_off + sz_deg + sz_rank + sz_bucket + sz_part;
    size_t need_A = need_B + sz_Y;

    int gE4 = (int)(((size_t)E + 1023) / 1024);       // 4 edges/thread
    int nb  = (N + SCAN_ELEMS - 1) / SCAN_ELEMS;      // 49, must be <= 64

    if (ws_size >= need_A && nb <= 64) {
        char* ws = (char*)d_ws;
        int*   off    = (int*)ws;   ws += sz_off;
        int*   deg    = (int*)ws;   ws += sz_deg;
        int*   rank   = (int*)ws;   ws += sz_rank;
        int*   bucket = (int*)ws;   ws += sz_bucket;
        int*   part   = (int*)ws;   ws += sz_part;
        float* Y      = (float*)ws;

        hipMemsetAsync(deg, 0, (size_t)N * sizeof(int), stream);
        k_deg<<<gE4, 256, 0, stream>>>(edst, deg, rank, E);
        k_part<<<nb, SCAN_BLK, 0, stream>>>(deg, part, N);
        k_final<<<nb, SCAN_BLK, 0, stream>>>(deg, part, off, N, E, nb);
        k_bucket<<<gE4, 256, 0, stream>>>(esrc, edst, off, rank, bucket, E);
        k_gemm<<<(N + 31) / 32, 256, 0, stream>>>(feature, W, Y, N);
        k_gather<<<(N + 3) / 4, 256, 0, stream>>>(Y, off, bucket, bias,
                                                  (float*)d_out, N);
    } else if (ws_size >= need_B && nb <= 64) {
        char* ws = (char*)d_ws;
        int* off    = (int*)ws;   ws += sz_off;
        int* deg    = (int*)ws;   ws += sz_deg;
        int* rank   = (int*)ws;   ws += sz_rank;
        int* bucket = (int*)ws;   ws += sz_bucket;
        int* part   = (int*)ws;

        hipMemsetAsync(deg, 0, (size_t)N * sizeof(int), stream);
        k_deg<<<gE4, 256, 0, stream>>>(edst, deg, rank, E);
        k_part<<<nb, SCAN_BLK, 0, stream>>>(deg, part, N);
        k_final<<<nb, SCAN_BLK, 0, stream>>>(deg, part, off, N, E, nb);
        k_bucket<<<gE4, 256, 0, stream>>>(esrc, edst, off, rank, bucket, E);
        k_node_fused<<<(N + 3) / 4, 256, 0, stream>>>(feature, off, bucket, W, bias,
                                                      (float*)d_out, N);
    } else {
        float* agg = (float*)d_out;
        float* cnt = (float*)d_ws;
        hipMemsetAsync(agg, 0, (size_t)N * F * sizeof(float), stream);
        hipMemsetAsync(cnt, 0, (size_t)N * sizeof(float), stream);
        long total = (long)E * F;
        gcn_edge_scatter<<<(int)((total + 255) / 256), 256, 0, stream>>>(
            feature, esrc, edst, agg, cnt, E);
        gcn_node_apply<<<(N + 3) / 4, 256, 0, stream>>>(feature, W, bias, cnt, agg, N);
    }
}

// Round 10
// 109.476 us; speedup vs baseline: 1.6290x; 1.0013x over previous
//
#include <hip/hip_runtime.h>

// GCN layer: out = relu( G(feature) @ W^T + b ), G = mean over in-edges (or
// identity for isolated nodes).  N=50000, F=64, E=800000.
//
// Structure: GEMM commutes with the (linear) aggregation:
//   G(feature) @ W^T == G(feature @ W^T)
// Pipeline: k_zero(deg) -> k_deg(rank) -> k_part/k_final(scan) ->
//           k_bucket(atomic-free) -> k_gemm(Y=feat@W^T) -> k_gather(mean+relu)
// Round-10 fix: hipMemsetAsync's fillBufferAligned took 45us for 195KB
// (4.7 GB/s, 8.7% occupancy tiny-grid fill) = 41% of total. Replaced with a
// 49-block int4 zero kernel.

#define F 64
#define SCAN_BLK 256
#define SCAN_ELEMS 1024   // elements scanned per block (4 per thread)

// ---------- K0: zero the degree array (int4 stores) ----------
__global__ __launch_bounds__(256) void k_zero(int* __restrict__ deg, int n4) {
    int i = blockIdx.x * 256 + threadIdx.x;
    if (i < n4) ((int4*)deg)[i] = make_int4(0, 0, 0, 0);
}

// ---------- K1: degree histogram + per-edge rank ----------
__global__ __launch_bounds__(256) void k_deg(const int* __restrict__ edst,
                                             int* __restrict__ deg,
                                             int* __restrict__ rank, int E) {
    int base = (blockIdx.x * 256 + threadIdx.x) * 4;
    if (base + 3 < E) {
        int4 d4 = *(const int4*)(edst + base);
        int r0 = atomicAdd(&deg[d4.x], 1);
        int r1 = atomicAdd(&deg[d4.y], 1);
        int r2 = atomicAdd(&deg[d4.z], 1);
        int r3 = atomicAdd(&deg[d4.w], 1);
        *(int4*)(rank + base) = make_int4(r0, r1, r2, r3);
    } else {
        for (int e = base; e < E; ++e)
            rank[e] = atomicAdd(&deg[edst[e]], 1);
    }
}

// ---------- K2a: per-block partial sums ----------
__global__ __launch_bounds__(SCAN_BLK) void k_part(const int* __restrict__ deg,
                                                   int* __restrict__ part, int N) {
    int b = blockIdx.x, tid = threadIdx.x;
    int i0 = b * SCAN_ELEMS + tid * 4;
    int s = 0;
#pragma unroll
    for (int k = 0; k < 4; ++k) { int i = i0 + k; if (i < N) s += deg[i]; }
    for (int d = 32; d; d >>= 1) s += __shfl_down(s, d);
    __shared__ int red[4];
    int w = tid >> 6;
    if ((tid & 63) == 0) red[w] = s;
    __syncthreads();
    if (tid == 0) part[b] = red[0] + red[1] + red[2] + red[3];
}

// ---------- K2b: block-local scan with fused root scan (nb <= 64) ----------
__global__ __launch_bounds__(SCAN_BLK) void k_final(const int* __restrict__ deg,
                                                    const int* __restrict__ part,
                                                    int* __restrict__ off,
                                                    int N, int E, int nb) {
    int b = blockIdx.x, tid = threadIdx.x;
    __shared__ int s_base;
    if (tid < 64) {
        int v = (tid < nb) ? part[tid] : 0;
        for (int d = 1; d < 64; d <<= 1) {
            int t = __shfl_up(v, d);
            if (tid >= d) v += t;
        }
        if (tid == b) s_base = v - ((b < nb) ? part[b] : 0);  // exclusive
    }
    int i0 = b * SCAN_ELEMS + tid * 4;
    int v[4]; int s = 0;
#pragma unroll
    for (int k = 0; k < 4; ++k) { int i = i0 + k; v[k] = (i < N) ? deg[i] : 0; s += v[k]; }
    __shared__ int sc[SCAN_BLK];
    sc[tid] = s;
    __syncthreads();
    for (int d = 1; d < SCAN_BLK; d <<= 1) {
        int t = (tid >= d) ? sc[tid - d] : 0;
        __syncthreads();
        sc[tid] += t;
        __syncthreads();
    }
    int exc = sc[tid] - s;
    int run = s_base + exc;
#pragma unroll
    for (int k = 0; k < 4; ++k) {
        int i = i0 + k;
        if (i < N) { off[i] = run; run += v[k]; }
    }
    if (b == 0 && tid == 0) off[N] = E;
}

// ---------- K3: atomic-free bucket scatter ----------
__global__ __launch_bounds__(256) void k_bucket(const int* __restrict__ esrc,
                                                const int* __restrict__ edst,
                                                const int* __restrict__ off,
                                                const int* __restrict__ rank,
                                                int* __restrict__ bucket, int E) {
    int base = (blockIdx.x * 256 + threadIdx.x) * 4;
    if (base + 3 < E) {
        int4 d4 = *(const int4*)(edst + base);
        int4 r4 = *(const int4*)(rank + base);
        int4 s4 = *(const int4*)(esrc + base);
        bucket[off[d4.x] + r4.x] = s4.x;
        bucket[off[d4.y] + r4.y] = s4.y;
        bucket[off[d4.z] + r4.z] = s4.z;
        bucket[off[d4.w] + r4.w] = s4.w;
    } else {
        for (int e = base; e < E; ++e)
            bucket[off[edst[e]] + rank[e]] = esrc[e];
    }
}

// ---------- K4: Y = feature @ W^T (dense, coalesced) ----------
__global__ __launch_bounds__(256) void k_gemm(const float* __restrict__ feature,
                                              const float* __restrict__ W,
                                              float* __restrict__ Y, int N) {
    __shared__ float sWt[64 * 76];
    __shared__ float shh[32 * 72];
    int tid = threadIdx.x;
    for (int i = tid; i < 4096; i += 256) {
        int fo = i >> 6, k = i & 63;
        sWt[k * 76 + fo] = W[i];
    }
    int n0blk = blockIdx.x * 32;
    for (int i = tid; i < 512; i += 256) {        // 32 rows x 16 float4
        int r = i >> 4, c4 = i & 15;
        int n = n0blk + r;
        float4 v = make_float4(0.f, 0.f, 0.f, 0.f);
        if (n < N) v = ((const float4*)feature)[(long)n * 16 + c4];
        *(float4*)&shh[r * 72 + c4 * 4] = v;
    }
    __syncthreads();
    int npair = tid >> 4, foq = tid & 15;
    int r0 = npair * 2, r1 = r0 + 1;
    float a0=0,a1=0,a2=0,a3=0,b0=0,b1=0,b2=0,b3=0;
#pragma unroll 8
    for (int k = 0; k < 64; ++k) {
        float hA = shh[r0 * 72 + k];
        float hB = shh[r1 * 72 + k];
        float4 wv = *(const float4*)&sWt[k * 76 + foq * 4];
        a0 = fmaf(hA, wv.x, a0); a1 = fmaf(hA, wv.y, a1);
        a2 = fmaf(hA, wv.z, a2); a3 = fmaf(hA, wv.w, a3);
        b0 = fmaf(hB, wv.x, b0); b1 = fmaf(hB, wv.y, b1);
        b2 = fmaf(hB, wv.z, b2); b3 = fmaf(hB, wv.w, b3);
    }
    int nA = n0blk + r0, nB = n0blk + r1;
    if (nA < N) ((float4*)Y)[(long)nA * 16 + foq] = make_float4(a0, a1, a2, a3);
    if (nB < N) ((float4*)Y)[(long)nB * 16 + foq] = make_float4(b0, b1, b2, b3);
}

// ---------- K5: gather-mean over Y + bias + relu ----------
__global__ __launch_bounds__(256) void k_gather(const float* __restrict__ Y,
                                                const int* __restrict__ off,
                                                const int* __restrict__ bucket,
                                                const float* __restrict__ bias,
                                                float* __restrict__ out, int N) {
    int tid = threadIdx.x;
    int w = tid >> 6, lane = tid & 63;
    int g = lane >> 4, c = lane & 15;
    int n = blockIdx.x * 4 + w;
    if (n >= N) return;
    int beg = off[n], end = off[n + 1];
    int d = end - beg;
    const float4* Y4 = (const float4*)Y;
    float4 A = make_float4(0.f,0.f,0.f,0.f), B = A, C = A, Dv = A;
    int last = end - 1;
    for (int base = beg; base < end; base += 16) {
        int j0 = base + g, j1 = j0 + 4, j2 = j0 + 8, j3 = j0 + 12;
        int s0 = bucket[min(j0, last)];
        int s1 = bucket[min(j1, last)];
        int s2 = bucket[min(j2, last)];
        int s3 = bucket[min(j3, last)];
        float4 v0 = Y4[(long)s0 * 16 + c];
        float4 v1 = Y4[(long)s1 * 16 + c];
        float4 v2 = Y4[(long)s2 * 16 + c];
        float4 v3 = Y4[(long)s3 * 16 + c];
        if (j0 < end) { A.x += v0.x; A.y += v0.y; A.z += v0.z; A.w += v0.w; }
        if (j1 < end) { B.x += v1.x; B.y += v1.y; B.z += v1.z; B.w += v1.w; }
        if (j2 < end) { C.x += v2.x; C.y += v2.y; C.z += v2.z; C.w += v2.w; }
        if (j3 < end) { Dv.x += v3.x; Dv.y += v3.y; Dv.z += v3.z; Dv.w += v3.w; }
    }
    A.x += B.x + C.x + Dv.x;
    A.y += B.y + C.y + Dv.y;
    A.z += B.z + C.z + Dv.z;
    A.w += B.w + C.w + Dv.w;
    A.x += __shfl_xor(A.x, 16); A.x += __shfl_xor(A.x, 32);
    A.y += __shfl_xor(A.y, 16); A.y += __shfl_xor(A.y, 32);
    A.z += __shfl_xor(A.z, 16); A.z += __shfl_xor(A.z, 32);
    A.w += __shfl_xor(A.w, 16); A.w += __shfl_xor(A.w, 32);
    int fw = c * 4 + g;
    float hv;
    if (d > 0) {
        float sel = (g == 0) ? A.x : (g == 1) ? A.y : (g == 2) ? A.z : A.w;
        hv = sel / (float)d;
    } else {
        hv = Y[(long)n * F + fw];
    }
    out[(long)n * F + fw] = fmaxf(hv + bias[fw], 0.0f);
}

// ---------- fallback tier B: fused gather+GEMM ----------
__global__ __launch_bounds__(256) void k_node_fused(const float* __restrict__ feature,
                                                    const int* __restrict__ off,
                                                    const int* __restrict__ bucket,
                                                    const float* __restrict__ W,
                                                    const float* __restrict__ bias,
                                                    float* __restrict__ out, int N) {
    __shared__ float sWt[64 * 65];
    __shared__ float sh[4][64];
    int tid = threadIdx.x;
    for (int i = tid; i < 64 * 64; i += 256) {
        int fo = i >> 6, k = i & 63;
        sWt[k * 65 + fo] = W[i];
    }
    int w = tid >> 6, lane = tid & 63;
    int g = lane >> 4, c = lane & 15;
    int n = blockIdx.x * 4 + w;
    const float4* F4 = (const float4*)feature;
    if (n < N) {
        int beg = off[n], end = off[n + 1];
        int d = end - beg;
        float ax=0,ay=0,az=0,aw=0,bx=0,by=0,bz=0,bw=0;
        for (int base = beg; base < end; base += 8) {
            int i0 = base + g, i1 = base + 4 + g;
            int s0 = (i0 < end) ? bucket[i0] : 0;
            int s1 = (i1 < end) ? bucket[i1] : 0;
            float4 v0 = F4[(long)s0 * 16 + c];
            float4 v1 = F4[(long)s1 * 16 + c];
            if (i0 < end) { ax += v0.x; ay += v0.y; az += v0.z; aw += v0.w; }
            if (i1 < end) { bx += v1.x; by += v1.y; bz += v1.z; bw += v1.w; }
        }
        ax += bx; ay += by; az += bz; aw += bw;
        ax += __shfl_xor(ax, 16); ax += __shfl_xor(ax, 32);
        ay += __shfl_xor(ay, 16); ay += __shfl_xor(ay, 32);
        az += __shfl_xor(az, 16); az += __shfl_xor(az, 32);
        aw += __shfl_xor(aw, 16); aw += __shfl_xor(aw, 32);
        int fw = c * 4 + g;
        float hv;
        if (d > 0) {
            float sel = (g == 0) ? ax : (g == 1) ? ay : (g == 2) ? az : aw;
            hv = sel / (float)d;
        } else {
            hv = feature[(long)n * F + fw];
        }
        sh[w][fw] = hv;
    }
    __syncthreads();
    float acc = bias[lane];
#pragma unroll
    for (int k = 0; k < 64; ++k)
        acc = fmaf(sh[w][k], sWt[k * 65 + lane], acc);
    if (n < N) out[(long)n * F + lane] = fmaxf(acc, 0.0f);
}

// ---------- fallback tier C: pure atomic ----------
__global__ __launch_bounds__(256) void gcn_edge_scatter(const float* __restrict__ feature,
                                                        const int* __restrict__ esrc,
                                                        const int* __restrict__ edst,
                                                        float* __restrict__ agg,
                                                        float* __restrict__ cnt, int E) {
    int t = blockIdx.x * blockDim.x + threadIdx.x;
    int e = t >> 6, f = t & 63;
    if (e >= E) return;
    atomicAdd(&agg[(long)edst[e] * F + f], feature[(long)esrc[e] * F + f]);
    if (f == 0) atomicAdd(&cnt[edst[e]], 1.0f);
}
__global__ __launch_bounds__(256) void gcn_node_apply(const float* __restrict__ feature,
                                                      const float* __restrict__ W,
                                                      const float* __restrict__ bias,
                                                      const float* __restrict__ cnt,
                                                      float* __restrict__ inout, int N) {
    __shared__ float sWt[64 * 65];
    __shared__ float sh[4][64];
    int tid = threadIdx.x;
    for (int i = tid; i < 64 * 64; i += 256) {
        int fo = i >> 6, k = i & 63;
        sWt[k * 65 + fo] = W[i];
    }
    int w = tid >> 6, f = tid & 63;
    int n = blockIdx.x * 4 + w;
    float h = 0.0f;
    if (n < N) {
        float c = cnt[n];
        h = (c > 0.0f) ? inout[(long)n * F + f] / c : feature[(long)n * F + f];
    }
    sh[w][f] = h;
    __syncthreads();
    float acc = bias[f];
#pragma unroll
    for (int k = 0; k < 64; ++k) acc = fmaf(sh[w][k], sWt[k * 65 + f], acc);
    if (n < N) inout[(long)n * F + f] = fmaxf(acc, 0.0f);
}

extern "C" void kernel_launch(void* const* d_in, const int* in_sizes, int n_in,
                              void* d_out, int out_size, void* d_ws, size_t ws_size,
                              hipStream_t stream) {
    const float* feature = (const float*)d_in[0];
    const int*   esrc    = (const int*)d_in[1];
    const int*   edst    = (const int*)d_in[2];
    const float* W       = (const float*)d_in[3];
    const float* bias    = (const float*)d_in[4];

    int N = in_sizes[0] / F;   // 50000
    int E = in_sizes[1];       // 800000

    auto align256 = [](size_t x) { return (x + 255) & ~(size_t)255; };
    size_t sz_off    = align256((size_t)(N + 1) * sizeof(int));
    size_t sz_deg    = align256((size_t)N * sizeof(int));
    size_t sz_rank   = align256((size_t)E * sizeof(int));
    size_t sz_bucket = align256((size_t)E * sizeof(int));
    size_t sz_part   = align256(64 * sizeof(int));
    size_t sz_Y      = align256((size_t)N * F * sizeof(float));
    size_t need_B = sz_off + sz_deg + sz_rank + sz_bucket + sz_part;
    size_t need_A = need_B + sz_Y;

    int gE4 = (int)(((size_t)E + 1023) / 1024);       // 4 edges/thread
    int nb  = (N + SCAN_ELEMS - 1) / SCAN_ELEMS;      // 49, must be <= 64
    int n4  = (N + 3) / 4;                            // int4 count for k_zero
    int gZ  = (n4 + 255) / 256;

    if (ws_size >= need_A && nb <= 64) {
        char* ws = (char*)d_ws;
        int*   off    = (int*)ws;   ws += sz_off;
        int*   deg    = (int*)ws;   ws += sz_deg;
        int*   rank   = (int*)ws;   ws += sz_rank;
        int*   bucket = (int*)ws;   ws += sz_bucket;
        int*   part   = (int*)ws;   ws += sz_part;
        float* Y      = (float*)ws;

        k_zero<<<gZ, 256, 0, stream>>>(deg, n4);
        k_deg<<<gE4, 256, 0, stream>>>(edst, deg, rank, E);
        k_part<<<nb, SCAN_BLK, 0, stream>>>(deg, part, N);
        k_final<<<nb, SCAN_BLK, 0, stream>>>(deg, part, off, N, E, nb);
        k_bucket<<<gE4, 256, 0, stream>>>(esrc, edst, off, rank, bucket, E);
        k_gemm<<<(N + 31) / 32, 256, 0, stream>>>(feature, W, Y, N);
        k_gather<<<(N + 3) / 4, 256, 0, stream>>>(Y, off, bucket, bias,
                                                  (float*)d_out, N);
    } else if (ws_size >= need_B && nb <= 64) {
        char* ws = (char*)d_ws;
        int* off    = (int*)ws;   ws += sz_off;
        int* deg    = (int*)ws;   ws += sz_deg;
        int* rank   = (int*)ws;   ws += sz_rank;
        int* bucket = (int*)ws;   ws += sz_bucket;
        int* part   = (int*)ws;

        k_zero<<<gZ, 256, 0, stream>>>(deg, n4);
        k_deg<<<gE4, 256, 0, stream>>>(edst, deg, rank, E);
        k_part<<<nb, SCAN_BLK, 0, stream>>>(deg, part, N);
        k_final<<<nb, SCAN_BLK, 0, stream>>>(deg, part, off, N, E, nb);
        k_bucket<<<gE4, 256, 0, stream>>>(esrc, edst, off, rank, bucket, E);
        k_node_fused<<<(N + 3) / 4, 256, 0, stream>>>(feature, off, bucket, W, bias,
                                                      (float*)d_out, N);
    } else {
        float* agg = (float*)d_out;
        float* cnt = (float*)d_ws;
        hipMemsetAsync(agg, 0, (size_t)N * F * sizeof(float), stream);
        hipMemsetAsync(cnt, 0, (size_t)N * sizeof(float), stream);
        long total = (long)E * F;
        gcn_edge_scatter<<<(int)((total + 255) / 256), 256, 0, stream>>>(
            feature, esrc, edst, agg, cnt, E);
        gcn_node_apply<<<(N + 3) / 4, 256, 0, stream>>>(feature, W, bias, cnt, agg, N);
    }
}

// Round 11
// 107.740 us; speedup vs baseline: 1.6552x; 1.0161x over previous
//
#include <hip/hip_runtime.h>

// GCN layer: out = relu( G(feature) @ W^T + b ), G = mean over in-edges (or
// identity for isolated nodes).  N=50000, F=64, E=800000.
//
// Structure: GEMM commutes with the (linear) aggregation:
//   G(feature) @ W^T == G(feature @ W^T)
// Pipeline: k_zero -> k_deg(rank) -> k_part/k_final(scan) -> k_bucket ->
//           k_gemm(Ybf = bf16(feat@W^T)) -> k_gather(mean+bias+relu).
// Round-11: Y stored as bf16 (row = 128B): halves the 205MB logical gather
// traffic; 8 lanes x ushort8 cover a row -> 8 edges/load, 4 chains = 32
// edges/iter. bf16 RNE error <= 2^-9*|y| ~ 0.01 << 0.0369 threshold.

#define F 64
#define SCAN_BLK 256
#define SCAN_ELEMS 1024

typedef unsigned int uint;
typedef unsigned short ushort;

__device__ __forceinline__ ushort f2bf(float x) {
    uint u = __float_as_uint(x);
    u += 0x7FFFu + ((u >> 16) & 1u);   // round-to-nearest-even
    return (ushort)(u >> 16);
}

// ---------- K0: zero the degree array ----------
__global__ __launch_bounds__(256) void k_zero(int* __restrict__ deg, int n4) {
    int i = blockIdx.x * 256 + threadIdx.x;
    if (i < n4) ((int4*)deg)[i] = make_int4(0, 0, 0, 0);
}

// ---------- K1: degree histogram + per-edge rank ----------
__global__ __launch_bounds__(256) void k_deg(const int* __restrict__ edst,
                                             int* __restrict__ deg,
                                             int* __restrict__ rank, int E) {
    int base = (blockIdx.x * 256 + threadIdx.x) * 4;
    if (base + 3 < E) {
        int4 d4 = *(const int4*)(edst + base);
        int r0 = atomicAdd(&deg[d4.x], 1);
        int r1 = atomicAdd(&deg[d4.y], 1);
        int r2 = atomicAdd(&deg[d4.z], 1);
        int r3 = atomicAdd(&deg[d4.w], 1);
        *(int4*)(rank + base) = make_int4(r0, r1, r2, r3);
    } else {
        for (int e = base; e < E; ++e)
            rank[e] = atomicAdd(&deg[edst[e]], 1);
    }
}

// ---------- K2a: per-block partial sums ----------
__global__ __launch_bounds__(SCAN_BLK) void k_part(const int* __restrict__ deg,
                                                   int* __restrict__ part, int N) {
    int b = blockIdx.x, tid = threadIdx.x;
    int i0 = b * SCAN_ELEMS + tid * 4;
    int s = 0;
#pragma unroll
    for (int k = 0; k < 4; ++k) { int i = i0 + k; if (i < N) s += deg[i]; }
    for (int d = 32; d; d >>= 1) s += __shfl_down(s, d);
    __shared__ int red[4];
    int w = tid >> 6;
    if ((tid & 63) == 0) red[w] = s;
    __syncthreads();
    if (tid == 0) part[b] = red[0] + red[1] + red[2] + red[3];
}

// ---------- K2b: block scan + fused root scan (nb <= 64) ----------
__global__ __launch_bounds__(SCAN_BLK) void k_final(const int* __restrict__ deg,
                                                    const int* __restrict__ part,
                                                    int* __restrict__ off,
                                                    int N, int E, int nb) {
    int b = blockIdx.x, tid = threadIdx.x;
    __shared__ int s_base;
    if (tid < 64) {
        int v = (tid < nb) ? part[tid] : 0;
        for (int d = 1; d < 64; d <<= 1) {
            int t = __shfl_up(v, d);
            if (tid >= d) v += t;
        }
        if (tid == b) s_base = v - ((b < nb) ? part[b] : 0);
    }
    int i0 = b * SCAN_ELEMS + tid * 4;
    int v[4]; int s = 0;
#pragma unroll
    for (int k = 0; k < 4; ++k) { int i = i0 + k; v[k] = (i < N) ? deg[i] : 0; s += v[k]; }
    __shared__ int sc[SCAN_BLK];
    sc[tid] = s;
    __syncthreads();
    for (int d = 1; d < SCAN_BLK; d <<= 1) {
        int t = (tid >= d) ? sc[tid - d] : 0;
        __syncthreads();
        sc[tid] += t;
        __syncthreads();
    }
    int exc = sc[tid] - s;
    int run = s_base + exc;
#pragma unroll
    for (int k = 0; k < 4; ++k) {
        int i = i0 + k;
        if (i < N) { off[i] = run; run += v[k]; }
    }
    if (b == 0 && tid == 0) off[N] = E;
}

// ---------- K3: atomic-free bucket scatter ----------
__global__ __launch_bounds__(256) void k_bucket(const int* __restrict__ esrc,
                                                const int* __restrict__ edst,
                                                const int* __restrict__ off,
                                                const int* __restrict__ rank,
                                                int* __restrict__ bucket, int E) {
    int base = (blockIdx.x * 256 + threadIdx.x) * 4;
    if (base + 3 < E) {
        int4 d4 = *(const int4*)(edst + base);
        int4 r4 = *(const int4*)(rank + base);
        int4 s4 = *(const int4*)(esrc + base);
        bucket[off[d4.x] + r4.x] = s4.x;
        bucket[off[d4.y] + r4.y] = s4.y;
        bucket[off[d4.z] + r4.z] = s4.z;
        bucket[off[d4.w] + r4.w] = s4.w;
    } else {
        for (int e = base; e < E; ++e)
            bucket[off[edst[e]] + rank[e]] = esrc[e];
    }
}

// ---------- K4: Ybf = bf16( feature @ W^T ) ----------
__global__ __launch_bounds__(256) void k_gemm(const float* __restrict__ feature,
                                              const float* __restrict__ W,
                                              ushort* __restrict__ Ybf, int N) {
    __shared__ float sWt[64 * 76];
    __shared__ float shh[32 * 72];
    int tid = threadIdx.x;
    for (int i = tid; i < 4096; i += 256) {
        int fo = i >> 6, k = i & 63;
        sWt[k * 76 + fo] = W[i];
    }
    int n0blk = blockIdx.x * 32;
    for (int i = tid; i < 512; i += 256) {        // 32 rows x 16 float4
        int r = i >> 4, c4 = i & 15;
        int n = n0blk + r;
        float4 v = make_float4(0.f, 0.f, 0.f, 0.f);
        if (n < N) v = ((const float4*)feature)[(long)n * 16 + c4];
        *(float4*)&shh[r * 72 + c4 * 4] = v;
    }
    __syncthreads();
    int npair = tid >> 4, foq = tid & 15;
    int r0 = npair * 2, r1 = r0 + 1;
    float a0=0,a1=0,a2=0,a3=0,b0=0,b1=0,b2=0,b3=0;
#pragma unroll 8
    for (int k = 0; k < 64; ++k) {
        float hA = shh[r0 * 72 + k];
        float hB = shh[r1 * 72 + k];
        float4 wv = *(const float4*)&sWt[k * 76 + foq * 4];
        a0 = fmaf(hA, wv.x, a0); a1 = fmaf(hA, wv.y, a1);
        a2 = fmaf(hA, wv.z, a2); a3 = fmaf(hA, wv.w, a3);
        b0 = fmaf(hB, wv.x, b0); b1 = fmaf(hB, wv.y, b1);
        b2 = fmaf(hB, wv.z, b2); b3 = fmaf(hB, wv.w, b3);
    }
    int nA = n0blk + r0, nB = n0blk + r1;
    if (nA < N) ((ushort4*)Ybf)[(long)nA * 16 + foq] =
        make_ushort4(f2bf(a0), f2bf(a1), f2bf(a2), f2bf(a3));
    if (nB < N) ((ushort4*)Ybf)[(long)nB * 16 + foq] =
        make_ushort4(f2bf(b0), f2bf(b1), f2bf(b2), f2bf(b3));
}

// ---------- K5: gather-mean over bf16 Y + bias + relu ----------
// lane = (g<<3)|c : g = edge slot 0..7, c = ushort8 column 0..7.
// One load per lane = 16B = 8 bf16; 8 lanes cover a 128B row; 8 rows/instr.
__global__ __launch_bounds__(256) void k_gather(const ushort* __restrict__ Ybf,
                                                const int* __restrict__ off,
                                                const int* __restrict__ bucket,
                                                const float* __restrict__ bias,
                                                float* __restrict__ out, int N) {
    int tid = threadIdx.x;
    int w = tid >> 6, lane = tid & 63;
    int g = lane >> 3, c = lane & 7;
    int n = blockIdx.x * 4 + w;
    if (n >= N) return;
    int beg = off[n], end = off[n + 1];
    int d = end - beg;
    const uint4* Y16 = (const uint4*)Ybf;       // 8 bf16 per uint4
    float acc[4][8];
#pragma unroll
    for (int ch = 0; ch < 4; ++ch)
#pragma unroll
        for (int j = 0; j < 8; ++j) acc[ch][j] = 0.f;
    int last = end - 1;
    for (int base = beg; base < end; base += 32) {
#pragma unroll
        for (int ch = 0; ch < 4; ++ch) {
            int jdx = base + ch * 8 + g;
            int s = bucket[min(jdx, last)];
            uint4 q = Y16[(long)s * 8 + c];
            if (jdx < end) {
                acc[ch][0] += __uint_as_float(q.x << 16);
                acc[ch][1] += __uint_as_float(q.x & 0xFFFF0000u);
                acc[ch][2] += __uint_as_float(q.y << 16);
                acc[ch][3] += __uint_as_float(q.y & 0xFFFF0000u);
                acc[ch][4] += __uint_as_float(q.z << 16);
                acc[ch][5] += __uint_as_float(q.z & 0xFFFF0000u);
                acc[ch][6] += __uint_as_float(q.w << 16);
                acc[ch][7] += __uint_as_float(q.w & 0xFFFF0000u);
            }
        }
    }
#pragma unroll
    for (int j = 0; j < 8; ++j)
        acc[0][j] += (acc[1][j] + acc[2][j]) + acc[3][j];
    // reduce across the 8 g-groups (lane bits 3,4,5)
#pragma unroll
    for (int j = 0; j < 8; ++j) {
        float v = acc[0][j];
        v += __shfl_xor(v, 8);
        v += __shfl_xor(v, 16);
        v += __shfl_xor(v, 32);
        acc[0][j] = v;
    }
    // this lane owns output feature fw = c*8 + g  -> select element g
    float sel = acc[0][0];
#pragma unroll
    for (int j = 1; j < 8; ++j) sel = (g == j) ? acc[0][j] : sel;
    int fw = c * 8 + g;
    float hv;
    if (d > 0) {
        hv = sel / (float)d;
    } else {
        hv = __uint_as_float(((uint)Ybf[(long)n * F + fw]) << 16);
    }
    out[(long)n * F + fw] = fmaxf(hv + bias[fw], 0.0f);
}

// ---------- fallback tier B: fused gather+GEMM (f32 path) ----------
__global__ __launch_bounds__(256) void k_node_fused(const float* __restrict__ feature,
                                                    const int* __restrict__ off,
                                                    const int* __restrict__ bucket,
                                                    const float* __restrict__ W,
                                                    const float* __restrict__ bias,
                                                    float* __restrict__ out, int N) {
    __shared__ float sWt[64 * 65];
    __shared__ float sh[4][64];
    int tid = threadIdx.x;
    for (int i = tid; i < 64 * 64; i += 256) {
        int fo = i >> 6, k = i & 63;
        sWt[k * 65 + fo] = W[i];
    }
    int w = tid >> 6, lane = tid & 63;
    int g = lane >> 4, c = lane & 15;
    int n = blockIdx.x * 4 + w;
    const float4* F4 = (const float4*)feature;
    if (n < N) {
        int beg = off[n], end = off[n + 1];
        int d = end - beg;
        float ax=0,ay=0,az=0,aw=0,bx=0,by=0,bz=0,bw=0;
        for (int base = beg; base < end; base += 8) {
            int i0 = base + g, i1 = base + 4 + g;
            int s0 = (i0 < end) ? bucket[i0] : 0;
            int s1 = (i1 < end) ? bucket[i1] : 0;
            float4 v0 = F4[(long)s0 * 16 + c];
            float4 v1 = F4[(long)s1 * 16 + c];
            if (i0 < end) { ax += v0.x; ay += v0.y; az += v0.z; aw += v0.w; }
            if (i1 < end) { bx += v1.x; by += v1.y; bz += v1.z; bw += v1.w; }
        }
        ax += bx; ay += by; az += bz; aw += bw;
        ax += __shfl_xor(ax, 16); ax += __shfl_xor(ax, 32);
        ay += __shfl_xor(ay, 16); ay += __shfl_xor(ay, 32);
        az += __shfl_xor(az, 16); az += __shfl_xor(az, 32);
        aw += __shfl_xor(aw, 16); aw += __shfl_xor(aw, 32);
        int fw = c * 4 + g;
        float hv;
        if (d > 0) {
            float selv = (g == 0) ? ax : (g == 1) ? ay : (g == 2) ? az : aw;
            hv = selv / (float)d;
        } else {
            hv = feature[(long)n * F + fw];
        }
        sh[w][fw] = hv;
    }
    __syncthreads();
    float acc = bias[lane];
#pragma unroll
    for (int k = 0; k < 64; ++k)
        acc = fmaf(sh[w][k], sWt[k * 65 + lane], acc);
    if (n < N) out[(long)n * F + lane] = fmaxf(acc, 0.0f);
}

// ---------- fallback tier C: pure atomic ----------
__global__ __launch_bounds__(256) void gcn_edge_scatter(const float* __restrict__ feature,
                                                        const int* __restrict__ esrc,
                                                        const int* __restrict__ edst,
                                                        float* __restrict__ agg,
                                                        float* __restrict__ cnt, int E) {
    int t = blockIdx.x * blockDim.x + threadIdx.x;
    int e = t >> 6, f = t & 63;
    if (e >= E) return;
    atomicAdd(&agg[(long)edst[e] * F + f], feature[(long)esrc[e] * F + f]);
    if (f == 0) atomicAdd(&cnt[edst[e]], 1.0f);
}
__global__ __launch_bounds__(256) void gcn_node_apply(const float* __restrict__ feature,
                                                      const float* __restrict__ W,
                                                      const float* __restrict__ bias,
                                                      const float* __restrict__ cnt,
                                                      float* __restrict__ inout, int N) {
    __shared__ float sWt[64 * 65];
    __shared__ float sh[4][64];
    int tid = threadIdx.x;
    for (int i = tid; i < 64 * 64; i += 256) {
        int fo = i >> 6, k = i & 63;
        sWt[k * 65 + fo] = W[i];
    }
    int w = tid >> 6, f = tid & 63;
    int n = blockIdx.x * 4 + w;
    float h = 0.0f;
    if (n < N) {
        float c = cnt[n];
        h = (c > 0.0f) ? inout[(long)n * F + f] / c : feature[(long)n * F + f];
    }
    sh[w][f] = h;
    __syncthreads();
    float acc = bias[f];
#pragma unroll
    for (int k = 0; k < 64; ++k) acc = fmaf(sh[w][k], sWt[k * 65 + f], acc);
    if (n < N) inout[(long)n * F + f] = fmaxf(acc, 0.0f);
}

extern "C" void kernel_launch(void* const* d_in, const int* in_sizes, int n_in,
                              void* d_out, int out_size, void* d_ws, size_t ws_size,
                              hipStream_t stream) {
    const float* feature = (const float*)d_in[0];
    const int*   esrc    = (const int*)d_in[1];
    const int*   edst    = (const int*)d_in[2];
    const float* W       = (const float*)d_in[3];
    const float* bias    = (const float*)d_in[4];

    int N = in_sizes[0] / F;   // 50000
    int E = in_sizes[1];       // 800000

    auto align256 = [](size_t x) { return (x + 255) & ~(size_t)255; };
    size_t sz_off    = align256((size_t)(N + 1) * sizeof(int));
    size_t sz_deg    = align256((size_t)N * sizeof(int));
    size_t sz_rank   = align256((size_t)E * sizeof(int));
    size_t sz_bucket = align256((size_t)E * sizeof(int));
    size_t sz_part   = align256(64 * sizeof(int));
    size_t sz_Y      = align256((size_t)N * F * sizeof(ushort));   // bf16
    size_t need_B = sz_off + sz_deg + sz_rank + sz_bucket + sz_part;
    size_t need_A = need_B + sz_Y;

    int gE4 = (int)(((size_t)E + 1023) / 1024);
    int nb  = (N + SCAN_ELEMS - 1) / SCAN_ELEMS;      // 49, must be <= 64
    int n4  = (N + 3) / 4;
    int gZ  = (n4 + 255) / 256;

    if (ws_size >= need_A && nb <= 64) {
        char* ws = (char*)d_ws;
        int*    off    = (int*)ws;    ws += sz_off;
        int*    deg    = (int*)ws;    ws += sz_deg;
        int*    rank   = (int*)ws;    ws += sz_rank;
        int*    bucket = (int*)ws;    ws += sz_bucket;
        int*    part   = (int*)ws;    ws += sz_part;
        ushort* Ybf    = (ushort*)ws;

        k_zero<<<gZ, 256, 0, stream>>>(deg, n4);
        k_deg<<<gE4, 256, 0, stream>>>(edst, deg, rank, E);
        k_part<<<nb, SCAN_BLK, 0, stream>>>(deg, part, N);
        k_final<<<nb, SCAN_BLK, 0, stream>>>(deg, part, off, N, E, nb);
        k_bucket<<<gE4, 256, 0, stream>>>(esrc, edst, off, rank, bucket, E);
        k_gemm<<<(N + 31) / 32, 256, 0, stream>>>(feature, W, Ybf, N);
        k_gather<<<(N + 3) / 4, 256, 0, stream>>>(Ybf, off, bucket, bias,
                                                  (float*)d_out, N);
    } else if (ws_size >= need_B && nb <= 64) {
        char* ws = (char*)d_ws;
        int* off    = (int*)ws;   ws += sz_off;
        int* deg    = (int*)ws;   ws += sz_deg;
        int* rank   = (int*)ws;   ws += sz_rank;
        int* bucket = (int*)ws;   ws += sz_bucket;
        int* part   = (int*)ws;

        k_zero<<<gZ, 256, 0, stream>>>(deg, n4);
        k_deg<<<gE4, 256, 0, stream>>>(edst, deg, rank, E);
        k_part<<<nb, SCAN_BLK, 0, stream>>>(deg, part, N);
        k_final<<<nb, SCAN_BLK, 0, stream>>>(deg, part, off, N, E, nb);
        k_bucket<<<gE4, 256, 0, stream>>>(esrc, edst, off, rank, bucket, E);
        k_node_fused<<<(N + 3) / 4, 256, 0, stream>>>(feature, off, bucket, W, bias,
                                                      (float*)d_out, N);
    } else {
        float* agg = (float*)d_out;
        float* cnt = (float*)d_ws;
        hipMemsetAsync(agg, 0, (size_t)N * F * sizeof(float), stream);
        hipMemsetAsync(cnt, 0, (size_t)N * sizeof(float), stream);
        long total = (long)E * F;
        gcn_edge_scatter<<<(int)((total + 255) / 256), 256, 0, stream>>>(
            feature, esrc, edst, agg, cnt, E);
        gcn_node_apply<<<(N + 3) / 4, 256, 0, stream>>>(feature, W, bias, cnt, agg, N);
    }
}